// Round 18
// baseline (45.510 us; speedup 1.0000x reference)
//
#include <hip/hip_runtime.h>
#include <stdint.h>

#define INPUT_SCALE 0.0078125f   // 2^-7

// Padded plane-split packed-x geometry:
//   plane p (0: ch 0-15, 1: ch 16-31), image n, 130x130 px, 16 B/px.
#define RB   (130 * 16)           // padded row stride bytes = 2080
#define IB   (130 * RB)           // image stride = 270,400 B
#define PB   (16 * IB)            // plane stride = 4,326,400 B

__device__ __forceinline__ uint32_t sadu8(uint32_t a, uint32_t b, uint32_t c) {
#if __has_builtin(__builtin_amdgcn_sad_u8)
    return __builtin_amdgcn_sad_u8(a, b, c);
#else
    uint32_t d;
    asm("v_sad_u8 %0, %1, %2, %3" : "=v"(d) : "v"(a), "v"(b), "v"(c));
    return d;
#endif
}

__device__ __forceinline__ uint32_t qbyte(float x) {
    // round(clip(x*128, -127, 127)) + 128  (rintf = round-half-even, matches jnp.round)
    float v = fminf(fmaxf(x * 128.0f, -127.0f), 127.0f);
    return (uint32_t)((int)rintf(v) + 128);
}

// ---------------- Kernel A: weight scale+pack (block 0) + border fill ----------------
// qwp layout: u = (((t*4 + fg)*8 + fl)*8 + cg); per (tap, fg) 256 B contiguous
// -> ONE s_load chunk (64 SGPRs) per tap in conv.
__global__ __launch_bounds__(1024) void quant_weight_border(const float* __restrict__ w,
                                                            uint32_t* __restrict__ qwp,
                                                            char* __restrict__ qxp) {
    int tid = threadIdx.x;
    if (blockIdx.x != 0) {
        // border fill: 2 planes x 16 imgs x 516 border px, one uint4 (16 B) each
        int idx = (blockIdx.x - 1) * 1024 + tid;      // 17*1024 = 17408 >= 16512
        if (idx < 16512) {
            int pn = idx / 516, i = idx - pn * 516;   // pn: plane*16+n
            int plane = pn >> 4, n = pn & 15;
            int r, c;
            if (i < 130)      { r = 0;   c = i; }
            else if (i < 260) { r = 129; c = i - 130; }
            else if (i < 388) { r = 1 + (i - 260); c = 0; }
            else              { r = 1 + (i - 388); c = 129; }
            uint4* p = (uint4*)(qxp + (size_t)plane * PB + (size_t)n * IB + r * RB + c * 16);
            *p = make_uint4(0x80808080u, 0x80808080u, 0x80808080u, 0x80808080u);
        }
        return;
    }
    __shared__ float red[1024];
    __shared__ float s_inv;
    float m = 0.0f;
    for (int i = tid; i < 9216; i += 1024) m = fmaxf(m, fabsf(w[i]));
    red[tid] = m;
    __syncthreads();
    for (int s = 512; s > 0; s >>= 1) {
        if (tid < s) red[tid] = fmaxf(red[tid], red[tid + s]);
        __syncthreads();
    }
    if (tid == 0) {
        float s = fmaxf(red[0] / 127.0f, 1e-8f);
        int e; float fr = frexpf(s, &e);            // s = fr * 2^e, fr in [0.5,1)
        int k = (fr >= 0.70710678118654752f) ? e : e - 1;  // round(log2(s))
        s_inv = exp2f((float)(-k));                 // 1/s_w, exact power of 2
    }
    __syncthreads();
    float inv = s_inv;
    for (int u = tid; u < 2304; u += 1024) {
        int cg = u & 7;
        int fl = (u >> 3) & 7;
        int fg = (u >> 6) & 3;
        int t  = u >> 8;
        int f = fg * 8 + fl;
        int kh = t / 3, kw = t - kh * 3;
        uint32_t pk = 0;
        #pragma unroll
        for (int b = 0; b < 4; ++b) {
            int c = cg * 4 + b;
            float v = w[((f * 32 + c) * 3 + kh) * 3 + kw] * inv;
            v = fminf(fmaxf(v, -127.0f), 127.0f);
            pk |= ((uint32_t)((int)rintf(v) + 128) & 0xFFu) << (8 * b);
        }
        qwp[u] = pk;
    }
}

// ---------------- Kernel B: quantize + pack x (plane-split, padded) ----------------
// Thread = 1 px: 32 coalesced channel loads (lane = w), 2 x 16 B coalesced writes.
__global__ __launch_bounds__(256) void quant_pack_x(const float* __restrict__ x,
                                                    char* __restrict__ qxp) {
    int t = blockIdx.x * 256 + threadIdx.x;          // 262144 threads
    int w = t & 127;
    int h = (t >> 7) & 127;
    int n = t >> 14;
    const float* xb = x + ((size_t)n * 32 * 128 + h) * 128 + w;
    uint32_t lo[4] = {0, 0, 0, 0}, hi[4] = {0, 0, 0, 0};
    #pragma unroll
    for (int c = 0; c < 16; ++c)
        lo[c >> 2] |= qbyte(xb[(size_t)c * 16384]) << ((c & 3) * 8);
    #pragma unroll
    for (int c = 0; c < 16; ++c)
        hi[c >> 2] |= qbyte(xb[(size_t)(c + 16) * 16384]) << ((c & 3) * 8);
    size_t off = (size_t)n * IB + (h + 1) * RB + (w + 1) * 16;
    *(uint4*)(qxp + off)      = make_uint4(lo[0], lo[1], lo[2], lo[3]);
    *(uint4*)(qxp + off + PB) = make_uint4(hi[0], hi[1], hi[2], hi[3]);
}

// ---------------- Kernel C: SAD conv — no LDS, no barrier, split counters ----------------
// 2048 blocks x 256 thr (4 waves). Wave = one 8-filter group; lane = col c (64-wide);
// thread = 2 rows (h, h+1) x 8 filters. Per tap: 4 global_load_dwordx4 (vmcnt,
// prefetched 1 tap ahead, L1/L2-hit) + ONE 256 B uniform s_load (lgkm = weights
// ONLY -> short K$ wait, no ds/smem mixing drain) + 128 sads (512 cy busy).
__global__ __launch_bounds__(256, 4) void adder_conv(const char* __restrict__ qxp,
                                                     const uint32_t* __restrict__ qwp,
                                                     float* __restrict__ out) {
    int tid = threadIdx.x;
    // XCD swizzle: 2048 blocks, XCD k gets 256 consecutive work ids (1 image each).
    int b = ((blockIdx.x & 7) << 8) | (blockIdx.x >> 3);
    int cc = b & 1;                  // col chunk (64 cols)
    int rp = (b >> 1) & 63;          // row pair
    int n  = b >> 7;                 // image
    int fg = __builtin_amdgcn_readfirstlane(tid >> 6);
    int c  = tid & 63;
    int h  = rp * 2;
    int gw = cc * 64 + c;

    // lane base: padded rows h+kh, padded cols gw+kw (border absorbs edges)
    const char* base = qxp + (size_t)n * IB + (size_t)h * RB + (size_t)gw * 16;

    uint32_t acc[2][8];
    #pragma unroll
    for (int r = 0; r < 2; ++r)
        #pragma unroll
        for (int f = 0; f < 8; ++f) acc[r][f] = 0u;

    // prefetch tap 0 (kh=0, kw=0)
    uint4 c00 = *(const uint4*)(base);
    uint4 c01 = *(const uint4*)(base + PB);
    uint4 c10 = *(const uint4*)(base + RB);
    uint4 c11 = *(const uint4*)(base + RB + PB);

    #pragma unroll 1
    for (int t = 0; t < 9; ++t) {
        uint4 n00, n01, n10, n11;
        if (t < 8) {                                  // scalar branch: prefetch t+1
            int t1 = t + 1;
            int kh1 = t1 / 3, kw1 = t1 - kh1 * 3;
            const char* p = base + kh1 * RB + kw1 * 16;
            n00 = *(const uint4*)(p);
            n01 = *(const uint4*)(p + PB);
            n10 = *(const uint4*)(p + RB);
            n11 = *(const uint4*)(p + RB + PB);
        }
        const uint32_t* wt = qwp + ((t << 2) + fg) * 64;   // uniform -> one s_load chunk
        #pragma unroll
        for (int f = 0; f < 8; ++f) {
            const uint4* wp = (const uint4*)(wt + f * 8);
            uint4 wv0 = wp[0], wv1 = wp[1];
            uint32_t a = acc[0][f];
            a = sadu8(c00.x, wv0.x, a);
            a = sadu8(c00.y, wv0.y, a);
            a = sadu8(c00.z, wv0.z, a);
            a = sadu8(c00.w, wv0.w, a);
            a = sadu8(c01.x, wv1.x, a);
            a = sadu8(c01.y, wv1.y, a);
            a = sadu8(c01.z, wv1.z, a);
            a = sadu8(c01.w, wv1.w, a);
            acc[0][f] = a;
            uint32_t d = acc[1][f];
            d = sadu8(c10.x, wv0.x, d);
            d = sadu8(c10.y, wv0.y, d);
            d = sadu8(c10.z, wv0.z, d);
            d = sadu8(c10.w, wv0.w, d);
            d = sadu8(c11.x, wv1.x, d);
            d = sadu8(c11.y, wv1.y, d);
            d = sadu8(c11.z, wv1.z, d);
            d = sadu8(c11.w, wv1.w, d);
            acc[1][f] = d;
        }
        c00 = n00; c01 = n01; c10 = n10; c11 = n11;
    }

    size_t obase = ((size_t)(n * 32 + fg * 8) * 16384) + (size_t)h * 128 + gw;
    #pragma unroll
    for (int f = 0; f < 8; ++f) {
        out[obase + (size_t)f * 16384]       = -(float)acc[0][f] * INPUT_SCALE;
        out[obase + (size_t)f * 16384 + 128] = -(float)acc[1][f] * INPUT_SCALE;
    }
}

extern "C" void kernel_launch(void* const* d_in, const int* in_sizes, int n_in,
                              void* d_out, int out_size, void* d_ws, size_t ws_size,
                              hipStream_t stream) {
    const float* x = (const float*)d_in[0];       // (16,32,128,128)
    const float* w = (const float*)d_in[1];       // (32,32,3,3)
    float* out = (float*)d_out;                   // (16,32,128,128)

    uint32_t* qwp = (uint32_t*)d_ws;              // 9216 B
    char* qxp = (char*)d_ws + 16384;              // 2 * PB = 8,652,800 B

    quant_weight_border<<<18, 1024, 0, stream>>>(w, qwp, qxp);
    quant_pack_x<<<1024, 256, 0, stream>>>(x, qxp);
    adder_conv<<<2048, 256, 0, stream>>>(qxp, qwp, out);
}